// Round 5
// baseline (84.745 us; speedup 1.0000x reference)
//
#include <hip/hip_runtime.h>
#include <math.h>

// S4 Vandermonde kernel: K[h,l] = 2*Re( sum_n Ct[h,n] * exp(dtA[h,n])^l )
//   dt  = exp(log_dt);  A = -exp(log_A_real) - i*A_imag;  dtA = A*dt
//   Ct  = C * (exp(dtA)-1) / A
// H=1024, NH=32, L=4096 (fixed).
//
// Round-5 structure: ONE block per h (tables built once per h, not 4x),
// 512 threads. Thread t owns l = t + 512k, k=0..7.
//  - Startup V = 2*Ct*exp(dtA*t) from two LDS tables (W16'[t>>4] 32 entries,
//    W1[t&15] 16 entries per n) -> zero per-thread transcendentals.
//  - Outputs via stable 2nd-order real recurrence along k (stride 512):
//    u_k = 2Re(W)*u_{k-1} - |W|^2*u_{k-2},  W = exp(dtA*512).
//  - WAVE-uniform gate: wave w (min l = 64w) skips n entirely when
//    re*64w < -16 (term < 1.1e-7; threshold is 2.6e-2). No divergence;
//    wave 0 never skips.

#define HH 1024
#define NH 32
#define LL 4096
#define BLOCK 512
#define KCH 8
#define STRIDE 512

#define TWO_PI 6.28318530717958647692f
#define INV_TWO_PI 0.15915494309189533577f

__device__ __forceinline__ float sin_rev(float r) {  // r in [0,1) revolutions
    float d;
    asm("v_sin_f32 %0, %1" : "=v"(d) : "v"(r));
    return d;
}
__device__ __forceinline__ float cos_rev(float r) {
    float d;
    asm("v_cos_f32 %0, %1" : "=v"(d) : "v"(r));
    return d;
}

__global__ __launch_bounds__(BLOCK) void s4_vandermonde(
    const float* __restrict__ C,            // [H][NH][2]
    const float* __restrict__ log_dt,       // [H]
    const float* __restrict__ log_A_real,   // [H][NH]
    const float* __restrict__ A_imag,       // [H][NH]
    float* __restrict__ out)                // [H][LL]
{
    __shared__ float2 sW16[NH][32];  // 2*Ct*exp(dtA*16a), a<32
    __shared__ float2 sW1[NH][16];   // exp(dtA*b), b<16
    __shared__ float4 sP[NH];        // {re, Wr, Wi, bS=|W|^2}
    __shared__ float4 sAux[NH];      // {fm, ctr, cti, re}

    const int h = blockIdx.x;
    const int t = threadIdx.x;

    // ---- phase 0: per-n scalars (lanes 0..31) ----
    if (t < NH) {
        const int n = t;
        const float dt  = __expf(log_dt[h]);
        const float Are = -__expf(log_A_real[h * NH + n]);
        const float Aim = -A_imag[h * NH + n];
        const float re = Are * dt;               // Re(dtA), negative
        const float im = Aim * dt;               // Im(dtA)
        float s1, c1;
        __sincosf(im, &s1, &c1);
        const float er1 = __expf(re);
        const float X = er1 * c1 - 1.0f;
        const float Y = er1 * s1;
        const float C0 = C[(h * NH + n) * 2 + 0];
        const float C1 = C[(h * NH + n) * 2 + 1];
        const float nr = C0 * X - C1 * Y;
        const float ni = C0 * Y + C1 * X;
        const float inv = 2.0f / (Are * Are + Aim * Aim);  // folds final x2
        const float ctr = (nr * Are + ni * Aim) * inv;
        const float cti = (ni * Are - nr * Aim) * inv;
        const float fm = im * INV_TWO_PI;        // revolutions per unit l

        // W = exp(dtA * 512), double-precision phase reduction
        const float erS = __expf(re * 512.0f);   // underflows cleanly to 0
        double revd = (double)fm * 512.0;
        revd -= floor(revd);
        float sS, cS;
        __sincosf((float)revd * TWO_PI, &sS, &cS);

        sP[n]   = make_float4(re, erS * cS, erS * sS, erS * erS);
        sAux[n] = make_float4(fm, ctr, cti, re);
    }
    __syncthreads();

    // ---- phase 1: build tables. 32n*(16+32)=1536 entries, 3 per thread ----
#pragma unroll
    for (int q = 0; q < 3; ++q) {
        const int idx = t + q * BLOCK;           // [0,1536)
        const int n = idx / 48;                  // magic-mul div
        const int j = idx - n * 48;              // [0,48)
        const float4 aux = sAux[n];
        const float fm = aux.x, ctr = aux.y, cti = aux.z, re = aux.w;
        if (j < 16) {
            const float m = (float)j;            // W1[j] = exp(dtA*j)
            const float er = __expf(re * m);
            float rev = fm * m;
            rev -= floorf(rev);
            sW1[n][j] = make_float2(er * cos_rev(rev), er * sin_rev(rev));
        } else {
            const int a = j - 16;                // W16'[a] = 2Ct*exp(dtA*16a)
            const float m = (float)(a * 16);
            const float er = __expf(re * m);
            float rev = fm * m;
            rev -= floorf(rev);
            const float br = er * cos_rev(rev);
            const float bi = er * sin_rev(rev);
            sW16[n][a] = make_float2(ctr * br - cti * bi, ctr * bi + cti * br);
        }
    }
    __syncthreads();

    // ---- main loop ----
    float acc[KCH];
#pragma unroll
    for (int k = 0; k < KCH; ++k) acc[k] = 0.0f;

    const float wminf = (float)(t & ~63);        // wave's min l (uniform)
    const int hi = t >> 4, lo = t & 15;

    for (int n = 0; n < NH; ++n) {
        const float4 P = sP[n];                  // broadcast b128
        if (P.x * wminf < -16.0f) continue;      // wave-uniform skip
        const float2 a2 = sW16[n][hi];
        const float2 b2 = sW1[n][lo];
        const float vr = a2.x * b2.x - a2.y * b2.y;  // V = 2Ct*exp(dtA*t)
        const float vi = a2.x * b2.y + a2.y * b2.x;
        float u0 = vr;                           // Re(V*W^0)
        float u1 = vr * P.y - vi * P.z;          // Re(V*W^1)
        acc[0] += u0;
        acc[1] += u1;
        const float aS = P.y + P.y;              // 2*Re(W)
#pragma unroll
        for (int k = 2; k < KCH; ++k) {
            const float u2 = aS * u1 - P.w * u0;
            acc[k] += u2;
            u0 = u1; u1 = u2;
        }
    }

    float* o = out + h * LL + t;
#pragma unroll
    for (int k = 0; k < KCH; ++k) o[k * STRIDE] = acc[k];
}

extern "C" void kernel_launch(void* const* d_in, const int* in_sizes, int n_in,
                              void* d_out, int out_size, void* d_ws, size_t ws_size,
                              hipStream_t stream) {
    const float* C          = (const float*)d_in[0];   // [1024][32][2]
    const float* log_dt     = (const float*)d_in[1];   // [1024]
    const float* log_A_real = (const float*)d_in[2];   // [1024][32]
    const float* A_imag     = (const float*)d_in[3];   // [1024][32]
    float* out              = (float*)d_out;           // [1024][4096]

    s4_vandermonde<<<dim3(HH), dim3(BLOCK), 0, stream>>>(
        C, log_dt, log_A_real, A_imag, out);
}